// Round 20
// baseline (161.988 us; speedup 1.0000x reference)
//
#include <hip/hip_runtime.h>
#include <stdint.h>

// out[c,b,d] = sum_a in[a,b] * W[reg[c],a,d] + bias[reg[c],d]
#define A_DIM 512   // in_features  (K)
#define B_DIM 1024  // batch        (M)
#define D_DIM 512   // out_features (N)
#define NKT   16    // K-tiles of 32

typedef __bf16 bf16x8 __attribute__((ext_vector_type(8)));
typedef float f32x4 __attribute__((ext_vector_type(4)));
typedef unsigned u32x2 __attribute__((ext_vector_type(2)));

typedef __attribute__((address_space(1))) void gvoid_t;
typedef __attribute__((address_space(3))) void svoid_t;

#define WAITV4() asm volatile("s_waitcnt vmcnt(4)" ::: "memory")
#define WAITV0() asm volatile("s_waitcnt vmcnt(0)" ::: "memory")
#define LGKM0()  asm volatile("s_waitcnt lgkmcnt(0)" ::: "memory")
#define FENCE()  asm volatile("" ::: "memory")
#define BARRIER() do { FENCE(); __builtin_amdgcn_s_barrier(); FENCE(); } while (0)

// fp32 -> bf16 RNE (proven R1/R3/R5) — prepass
__device__ __forceinline__ unsigned short f2bf(float f) {
  union { float f; unsigned u; } x; x.f = f;
  unsigned r = x.u + 0x7fffu + ((x.u >> 16) & 1u);
  return (unsigned short)(r >> 16);
}

// packed fp32 pair -> bf16x2, one VALU op (R13-proven)
__device__ __forceinline__ unsigned pk2(float lo, float hi) {
  unsigned r;
  asm("v_cvt_pk_bf16_f32 %0, %1, %2" : "=v"(r) : "v"(lo), "v"(hi));
  return r;
}

__device__ __forceinline__ void gload16(const void* g, void* l) {
  __builtin_amdgcn_global_load_lds((gvoid_t*)g, (svoid_t*)l, 16, 0, 0);
}

// ---------------------------------------------------------------------------
// Prepass (X only): Xt[b][a] <- bf16(input[a][b]). R1-proven verbatim.
// ---------------------------------------------------------------------------
__global__ __launch_bounds__(256) void transpose_cvt(
    const float* __restrict__ src, unsigned short* __restrict__ dst,
    int M, int N) {
  __shared__ float T[64][65];
  const int t = threadIdx.x;
  const int m0 = blockIdx.y * 64, n0 = blockIdx.x * 64;

#pragma unroll
  for (int p = 0; p < 4; ++p) {
    const int mr = (t >> 4) + p * 16;
    const int n4 = (t & 15) * 4;
    const float4 v = *(const float4*)(src + (size_t)(m0 + mr) * N + n0 + n4);
    T[n4 + 0][mr] = v.x;
    T[n4 + 1][mr] = v.y;
    T[n4 + 2][mr] = v.z;
    T[n4 + 3][mr] = v.w;
  }
  __syncthreads();

#pragma unroll
  for (int p = 0; p < 2; ++p) {
    const int nr = (t >> 3) + p * 32;
    const int m8 = (t & 7) * 8;
    alignas(16) unsigned short tmp[8];
#pragma unroll
    for (int j = 0; j < 8; ++j) tmp[j] = f2bf(T[nr][m8 + j]);
    *(uint4*)(dst + (size_t)(n0 + nr) * M + m0 + m8) = *(const uint4*)tmp;
  }
}

// ---------------------------------------------------------------------------
// Fused GEMM: R13's exact block tile (256x128), loop order, LDS layouts, and
// epilogue — but 512 threads / 8 waves (wave-tile 64x64, acc=64 VGPR).
// SAME L2/HBM traffic per block, SAME barrier count; the ONLY change is
// occupancy: <=128 VGPR + launch_bounds(512,4) -> 2 blocks/CU = 4 waves/SIMD
// (vs R13's 2/SIMD) -> 2x latency-hiding TLP around the barrier-coupled
// serial segments. Per-wave per-tile VMEM = 4 ops (2 gload_lds + 2 float4)
// -> counted wait vmcnt(4) keeps tile T+1 in flight.
// ---------------------------------------------------------------------------
__global__ __launch_bounds__(512, 4) void mlgemm_fused(
    const unsigned short* __restrict__ Xt, const float* __restrict__ wtab,
    const float* __restrict__ bias_table, const int* __restrict__ regions,
    float* __restrict__ out) {
  __shared__ union SM {
    struct {
      alignas(16) unsigned short As[3][256][32];  // 48 KiB
      alignas(16) unsigned Bsu[2][16][130];       // 16.25 KiB
    } k;
    alignas(16) float slab[8][16 * 68];           // 34 KiB (epilogue reuse)
  } sm;

  const int bid = blockIdx.x;
  const int xcd = bid & 7, q = bid >> 3;
  const int c   = (q >> 4) * 8 + xcd;
  const int t16 = q & 15;
  const int b0     = (t16 & 3) * 256;
  const int d0blk  = (t16 >> 2) * 128;

  const int t = threadIdx.x;
  const int w = t >> 6, l = t & 63;              // 8 waves
  const int lr = l & 15, lg = l >> 4;
  const int wm = w >> 1, wn = w & 1;             // 4 (M) x 2 (N) waves
  const int h = regions[c];

  const unsigned short* Xbase = Xt + (size_t)b0 * A_DIM;
  const float* Wbase = wtab + (size_t)h * A_DIM * D_DIM + d0blk;

  f32x4 acc[4][4] = {};

  // A staging (R13-proven pattern): 16 gload16 groups / 8 waves = 2 per wave.
  const int a_src_chunk = (l & 3) ^ ((l >> 3) & 3);
  const int a_lrow = l >> 2;
  // B loader: thread covers k-pair kp = w*2 + (l>>5) (0..15), d-run 4*(l&31).
  const int kp = w * 2 + (l >> 5);
  const int bd0 = 4 * (l & 31);

  f32x4 bregE[2], bregO[2];

  auto issueA = [&](int T) {
    const int buf = T % 3;
    const int koff = T * 32 + a_src_chunk * 8;
#pragma unroll
    for (int i = 0; i < 2; ++i) {
      const int row0 = w * 32 + i * 16;
      gload16(Xbase + (size_t)(row0 + a_lrow) * A_DIM + koff, &sm.k.As[buf][row0][0]);
    }
  };
  auto ldB = [&](int T, f32x4 (&breg)[2]) {
    const float* p = Wbase + (size_t)(T * 32 + kp * 2) * D_DIM + bd0;
    breg[0] = *(const f32x4*)p;                   // k = 2kp
    breg[1] = *(const f32x4*)(p + D_DIM);         // k = 2kp+1
  };
  auto writeB = [&](int T, f32x4 (&breg)[2]) {
    unsigned pk[4];
#pragma unroll
    for (int i = 0; i < 4; ++i)
      pk[i] = pk2(breg[0][i], breg[1][i]);        // lo = k even, hi = k odd
    unsigned* dst = &sm.k.Bsu[T & 1][kp][bd0];
    *(u32x2*)(dst + 0) = u32x2{pk[0], pk[1]};
    *(u32x2*)(dst + 2) = u32x2{pk[2], pk[3]};
  };

  auto mfmaStep = [&](int T) {
    const int abuf = T % 3, bbuf = T & 1;
    bf16x8 av[4], bv[4];
#pragma unroll
    for (int m = 0; m < 4; ++m) {
      const int row = wm * 64 + m * 16 + lr;
      av[m] = *(const bf16x8*)&sm.k.As[abuf][row][(lg ^ ((lr >> 1) & 3)) * 8];
    }
#pragma unroll
    for (int n = 0; n < 4; ++n) {
      const int d = wn * 64 + n * 16 + lr;
      union { unsigned u[4]; bf16x8 v; } ub;
#pragma unroll
      for (int i = 0; i < 4; ++i) ub.u[i] = sm.k.Bsu[bbuf][4 * lg + i][d];
      bv[n] = ub.v;
    }
    __builtin_amdgcn_s_setprio(1);
#pragma unroll
    for (int m = 0; m < 4; ++m)
#pragma unroll
      for (int n = 0; n < 4; ++n)
        acc[m][n] = __builtin_amdgcn_mfma_f32_16x16x32_bf16(av[m], bv[n], acc[m][n], 0, 0, 0);
    __builtin_amdgcn_s_setprio(0);
  };

  // Bias in prologue.
  float bs[4];
#pragma unroll
  for (int n = 0; n < 4; ++n)
    bs[n] = bias_table[(size_t)h * D_DIM + d0blk + wn * 64 + n * 16 + lr];

  // Prologue: 2 tiles in flight (4 VMEM/wave/tile: 2 gload_lds + 2 float4).
  issueA(0); ldB(0, bregE);
  issueA(1); ldB(1, bregO);

  // R13-proven loop order: wait T -> writeB(T) -> barrier -> issue T+2 -> mfma.
#pragma unroll 1
  for (int T = 0; T < NKT - 2; T += 2) {
    WAITV4();                       // tile T's 4 done; T+1's stay in flight
    writeB(T, bregE);
    LGKM0(); BARRIER();
    issueA(T + 2); ldB(T + 2, bregE); FENCE();
    mfmaStep(T);

    WAITV4();
    writeB(T + 1, bregO);
    LGKM0(); BARRIER();
    issueA(T + 3); ldB(T + 3, bregO); FENCE();
    mfmaStep(T + 1);
  }
  WAITV4();
  writeB(NKT - 2, bregE);
  LGKM0(); BARRIER();
  mfmaStep(NKT - 2);
  WAITV0();
  writeB(NKT - 1, bregO);
  LGKM0(); BARRIER();
  mfmaStep(NKT - 1);

  // ---- Epilogue: slab -> nontemporal full-line stores (R9-proven) ----
  __syncthreads();   // all waves done reading As/Bsu before slab aliasing

  float* ob = out + (size_t)c * B_DIM * D_DIM;
  const int orow_base = b0 + wm * 64;
  const int ocol_base = d0blk + wn * 64;
#pragma unroll
  for (int g = 0; g < 4; ++g) {    // static unroll: acc indices compile-time
#pragma unroll
    for (int j = 0; j < 4; ++j) {
      const int row = lg * 4 + j;                 // 0..15
#pragma unroll
      for (int n = 0; n < 4; ++n)
        sm.slab[w][row * 68 + n * 16 + lr] = acc[g][n][j] + bs[n];
    }
    __syncthreads();   // cross-lane exchange (R6 fix)
#pragma unroll
    for (int r = 0; r < 4; ++r) {
      const int chunk = r * 64 + l;               // 0..255
      const int row = chunk >> 4, seg = chunk & 15;
      const f32x4 v = *(const f32x4*)&sm.slab[w][row * 68 + seg * 4];
      __builtin_nontemporal_store(
          v, (f32x4*)(ob + (size_t)(orow_base + g * 16 + row) * D_DIM +
                      ocol_base + seg * 4));
    }
    __syncthreads();   // slab reused next group
  }
}

// ---------------------------------------------------------------------------
// Fallback: naive fp32 (only if ws can't hold Xt).
// ---------------------------------------------------------------------------
__global__ __launch_bounds__(256) void naive_ml(
    const float* __restrict__ in, const int* __restrict__ regions,
    const float* __restrict__ wt, const float* __restrict__ bias,
    float* __restrict__ out) {
  const int d = blockIdx.x * 256 + threadIdx.x;
  const int b = blockIdx.y;
  const int cz = blockIdx.z;
  const int hh = regions[cz];
  const float* W = wt + (size_t)hh * A_DIM * D_DIM + d;
  float acc = bias[(size_t)hh * D_DIM + d];
  for (int a = 0; a < A_DIM; ++a) acc += in[(size_t)a * B_DIM + b] * W[(size_t)a * D_DIM];
  out[(size_t)cz * B_DIM * D_DIM + (size_t)b * D_DIM + d] = acc;
}

extern "C" void kernel_launch(void* const* d_in, const int* in_sizes, int n_in,
                              void* d_out, int out_size, void* d_ws, size_t ws_size,
                              hipStream_t stream) {
  const float* input = (const float*)d_in[0];
  const int* regions = (const int*)d_in[1];
  const float* wtab  = (const float*)d_in[2];
  const float* btab  = (const float*)d_in[3];
  float* out = (float*)d_out;
  const int C = in_sizes[1];  // n_regions = 128

  const size_t xt_bytes = (size_t)B_DIM * A_DIM * 2;  // 1 MB

  if (ws_size < xt_bytes) {
    naive_ml<<<dim3(D_DIM / 256, B_DIM, C), 256, 0, stream>>>(input, regions, wtab, btab, out);
    return;
  }

  unsigned short* Xt = (unsigned short*)d_ws;

  transpose_cvt<<<dim3(B_DIM / 64, A_DIM / 64), 256, 0, stream>>>(
      input, Xt, A_DIM, B_DIM);
  mlgemm_fused<<<dim3((B_DIM / 256) * (D_DIM / 128) * C), 512, 0, stream>>>(
      Xt, wtab, btab, regions, out);
}

// Round 21
// 110.220 us; speedup vs baseline: 1.4697x; 1.4697x over previous
//
#include <hip/hip_runtime.h>
#include <stdint.h>

// out[c,b,d] = sum_a in[a,b] * W[reg[c],a,d] + bias[reg[c],d]
#define A_DIM 512   // in_features  (K)
#define B_DIM 1024  // batch        (M)
#define D_DIM 512   // out_features (N)
#define NKT   16    // K-tiles of 32

typedef __bf16 bf16x8 __attribute__((ext_vector_type(8)));
typedef float f32x4 __attribute__((ext_vector_type(4)));
typedef unsigned u32x2 __attribute__((ext_vector_type(2)));

typedef __attribute__((address_space(1))) void gvoid_t;
typedef __attribute__((address_space(3))) void svoid_t;

#define WAITV8() asm volatile("s_waitcnt vmcnt(8)" ::: "memory")
#define WAITV0() asm volatile("s_waitcnt vmcnt(0)" ::: "memory")
#define LGKM0()  asm volatile("s_waitcnt lgkmcnt(0)" ::: "memory")
#define FENCE()  asm volatile("" ::: "memory")
#define BARRIER() do { FENCE(); __builtin_amdgcn_s_barrier(); FENCE(); } while (0)

// fp32 -> bf16 RNE (proven R1/R3/R5) — used in the prepass
__device__ __forceinline__ unsigned short f2bf(float f) {
  union { float f; unsigned u; } x; x.f = f;
  unsigned r = x.u + 0x7fffu + ((x.u >> 16) & 1u);
  return (unsigned short)(r >> 16);
}

// packed fp32 pair -> bf16x2 in one VALU op (lo = src0, hi = src1)
__device__ __forceinline__ unsigned pk2(float lo, float hi) {
  unsigned r;
  asm("v_cvt_pk_bf16_f32 %0, %1, %2" : "=v"(r) : "v"(lo), "v"(hi));
  return r;
}

__device__ __forceinline__ void gload16(const void* g, void* l) {
  __builtin_amdgcn_global_load_lds((gvoid_t*)g, (svoid_t*)l, 16, 0, 0);
}

// ---------------------------------------------------------------------------
// Prepass (X only): Xt[b][a] <- bf16(input[a][b]). R1-proven verbatim.
// ---------------------------------------------------------------------------
__global__ __launch_bounds__(256) void transpose_cvt(
    const float* __restrict__ src, unsigned short* __restrict__ dst,
    int M, int N) {
  __shared__ float T[64][65];
  const int t = threadIdx.x;
  const int m0 = blockIdx.y * 64, n0 = blockIdx.x * 64;

#pragma unroll
  for (int p = 0; p < 4; ++p) {
    const int mr = (t >> 4) + p * 16;
    const int n4 = (t & 15) * 4;
    const float4 v = *(const float4*)(src + (size_t)(m0 + mr) * N + n0 + n4);
    T[n4 + 0][mr] = v.x;
    T[n4 + 1][mr] = v.y;
    T[n4 + 2][mr] = v.z;
    T[n4 + 3][mr] = v.w;
  }
  __syncthreads();

#pragma unroll
  for (int p = 0; p < 2; ++p) {
    const int nr = (t >> 3) + p * 32;
    const int m8 = (t & 7) * 8;
    alignas(16) unsigned short tmp[8];
#pragma unroll
    for (int j = 0; j < 8; ++j) tmp[j] = f2bf(T[nr][m8 + j]);
    *(uint4*)(dst + (size_t)(n0 + nr) * M + m0 + m8) = *(const uint4*)tmp;
  }
}

// ---------------------------------------------------------------------------
// Fused GEMM (R13 verbatim — session best, 110.4 us reproduced twice):
// 256x128 tile, BK=32, 4 waves (2Mx2N), 2 K-tiles in flight, counted
// vmcnt(8), 1 barrier/tile, v_cvt_pk_bf16_f32 B-convert, setprio MFMA
// cluster, slab epilogue with full-line nontemporal stores. XCD-chunked
// decode keeps the 4 b0-sibling blocks of each W panel consecutive (L2
// reuse; R10 proved it worth ~23 us).
// ---------------------------------------------------------------------------
__global__ __launch_bounds__(256, 2) void mlgemm_fused(
    const unsigned short* __restrict__ Xt, const float* __restrict__ wtab,
    const float* __restrict__ bias_table, const int* __restrict__ regions,
    float* __restrict__ out) {
  __shared__ union SM {
    struct {
      alignas(16) unsigned short As[3][256][32];  // 48 KiB
      alignas(16) unsigned Bsu[2][16][130];       // 16.25 KiB
    } k;
    alignas(16) float slab[4][32 * 68];           // 34 KiB (epilogue reuse)
  } sm;

  const int bid = blockIdx.x;
  const int xcd = bid & 7, q = bid >> 3;
  const int c   = (q >> 4) * 8 + xcd;
  const int t16 = q & 15;
  const int b0     = (t16 & 3) * 256;
  const int d0blk  = (t16 >> 2) * 128;

  const int t = threadIdx.x;
  const int w = t >> 6, l = t & 63;
  const int lr = l & 15, lg = l >> 4;
  const int wm = w >> 1, wn = w & 1;             // 2 (M) x 2 (N) waves
  const int h = regions[c];

  const unsigned short* Xbase = Xt + (size_t)b0 * A_DIM;
  const float* Wbase = wtab + (size_t)h * A_DIM * D_DIM + d0blk;

  f32x4 acc[8][4] = {};

  const int a_src_chunk = (l & 3) ^ ((l >> 3) & 3);
  const int a_lrow = l >> 2;
  const int kp_base = (w & 1) * 4 + ((l >> 3) & 3);
  const int bd0 = 4 * (l & 7) + 32 * (l >> 5) + 64 * (w >> 1);

  f32x4 bregE[4], bregO[4];

  auto issueA = [&](int T) {
    const int buf = T % 3;
    const int koff = T * 32 + a_src_chunk * 8;
#pragma unroll
    for (int i = 0; i < 4; ++i) {
      const int row0 = w * 64 + i * 16;
      gload16(Xbase + (size_t)(row0 + a_lrow) * A_DIM + koff, &sm.k.As[buf][row0][0]);
    }
  };
  auto ldB = [&](int T, f32x4 (&breg)[4]) {
#pragma unroll
    for (int r = 0; r < 2; ++r) {
      const int kp = r * 8 + kp_base;
      const float* p = Wbase + (size_t)(T * 32 + kp * 2) * D_DIM + bd0;
      breg[r * 2 + 0] = *(const f32x4*)p;           // plain: keep L2 allocate
      breg[r * 2 + 1] = *(const f32x4*)(p + D_DIM);
    }
  };
  auto writeB = [&](int T, f32x4 (&breg)[4]) {
#pragma unroll
    for (int r = 0; r < 2; ++r) {
      const int kp = r * 8 + kp_base;
      unsigned pk[4];
#pragma unroll
      for (int i = 0; i < 4; ++i)
        pk[i] = pk2(breg[r * 2][i], breg[r * 2 + 1][i]);  // lo=k even, hi=k odd
      unsigned* dst = &sm.k.Bsu[T & 1][kp][bd0];
      *(u32x2*)(dst + 0) = u32x2{pk[0], pk[1]};
      *(u32x2*)(dst + 2) = u32x2{pk[2], pk[3]};
    }
  };

  auto mfmaStep = [&](int T) {
    const int abuf = T % 3, bbuf = T & 1;
    bf16x8 av[8], bv[4];
#pragma unroll
    for (int m = 0; m < 8; ++m) {
      const int row = wm * 128 + m * 16 + lr;
      av[m] = *(const bf16x8*)&sm.k.As[abuf][row][(lg ^ ((lr >> 1) & 3)) * 8];
    }
#pragma unroll
    for (int n = 0; n < 4; ++n) {
      const int d = wn * 64 + n * 16 + lr;
      union { unsigned u[4]; bf16x8 v; } ub;
#pragma unroll
      for (int i = 0; i < 4; ++i) ub.u[i] = sm.k.Bsu[bbuf][4 * lg + i][d];
      bv[n] = ub.v;
    }
    __builtin_amdgcn_s_setprio(1);
#pragma unroll
    for (int m = 0; m < 8; ++m)
#pragma unroll
      for (int n = 0; n < 4; ++n)
        acc[m][n] = __builtin_amdgcn_mfma_f32_16x16x32_bf16(av[m], bv[n], acc[m][n], 0, 0, 0);
    __builtin_amdgcn_s_setprio(0);
  };

  // Bias in prologue.
  float bs[4];
#pragma unroll
  for (int n = 0; n < 4; ++n)
    bs[n] = bias_table[(size_t)h * D_DIM + d0blk + wn * 64 + n * 16 + lr];

  // Prologue: 2 tiles in flight (8 VMEM/wave/tile: 4 gload_lds + 4 float4).
  issueA(0); ldB(0, bregE);
  issueA(1); ldB(1, bregO);

  // R9-proven loop order: wait T -> writeB(T) -> barrier -> issue T+2 -> mfma.
#pragma unroll 1
  for (int T = 0; T < NKT - 2; T += 2) {
    WAITV8();                       // tile T's 8 done; T+1's stay in flight
    writeB(T, bregE);
    LGKM0(); BARRIER();
    issueA(T + 2); ldB(T + 2, bregE); FENCE();
    mfmaStep(T);

    WAITV8();
    writeB(T + 1, bregO);
    LGKM0(); BARRIER();
    issueA(T + 3); ldB(T + 3, bregO); FENCE();
    mfmaStep(T + 1);
  }
  WAITV8();
  writeB(NKT - 2, bregE);
  LGKM0(); BARRIER();
  mfmaStep(NKT - 2);
  WAITV0();
  writeB(NKT - 1, bregO);
  LGKM0(); BARRIER();
  mfmaStep(NKT - 1);

  // ---- Epilogue: slab -> nontemporal full-line stores (R9-proven) ----
  __syncthreads();   // all waves done reading As/Bsu before slab aliasing

  float* ob = out + (size_t)c * B_DIM * D_DIM;
  const int orow_base = b0 + wm * 128;
  const int ocol_base = d0blk + wn * 64;
#pragma unroll
  for (int g = 0; g < 4; ++g) {
#pragma unroll
    for (int m2 = 0; m2 < 2; ++m2)
#pragma unroll
      for (int j = 0; j < 4; ++j) {
        const int row = m2 * 16 + lg * 4 + j;     // 0..31
#pragma unroll
        for (int n = 0; n < 4; ++n)
          sm.slab[w][row * 68 + n * 16 + lr] = acc[g * 2 + m2][n][j] + bs[n];
      }
    __syncthreads();   // cross-lane exchange (R6 fix)
#pragma unroll
    for (int r = 0; r < 8; ++r) {
      const int chunk = r * 64 + l;               // 0..511
      const int row = chunk >> 4, seg = chunk & 15;
      const f32x4 v = *(const f32x4*)&sm.slab[w][row * 68 + seg * 4];
      __builtin_nontemporal_store(
          v, (f32x4*)(ob + (size_t)(orow_base + g * 32 + row) * D_DIM +
                      ocol_base + seg * 4));
    }
    __syncthreads();   // slab reused next group
  }
}

// ---------------------------------------------------------------------------
// Fallback: naive fp32 (only if ws can't hold Xt).
// ---------------------------------------------------------------------------
__global__ __launch_bounds__(256) void naive_ml(
    const float* __restrict__ in, const int* __restrict__ regions,
    const float* __restrict__ wt, const float* __restrict__ bias,
    float* __restrict__ out) {
  const int d = blockIdx.x * 256 + threadIdx.x;
  const int b = blockIdx.y;
  const int cz = blockIdx.z;
  const int hh = regions[cz];
  const float* W = wt + (size_t)hh * A_DIM * D_DIM + d;
  float acc = bias[(size_t)hh * D_DIM + d];
  for (int a = 0; a < A_DIM; ++a) acc += in[(size_t)a * B_DIM + b] * W[(size_t)a * D_DIM];
  out[(size_t)cz * B_DIM * D_DIM + (size_t)b * D_DIM + d] = acc;
}

extern "C" void kernel_launch(void* const* d_in, const int* in_sizes, int n_in,
                              void* d_out, int out_size, void* d_ws, size_t ws_size,
                              hipStream_t stream) {
  const float* input = (const float*)d_in[0];
  const int* regions = (const int*)d_in[1];
  const float* wtab  = (const float*)d_in[2];
  const float* btab  = (const float*)d_in[3];
  float* out = (float*)d_out;
  const int C = in_sizes[1];  // n_regions = 128

  const size_t xt_bytes = (size_t)B_DIM * A_DIM * 2;  // 1 MB

  if (ws_size < xt_bytes) {
    naive_ml<<<dim3(D_DIM / 256, B_DIM, C), 256, 0, stream>>>(input, regions, wtab, btab, out);
    return;
  }

  unsigned short* Xt = (unsigned short*)d_ws;

  transpose_cvt<<<dim3(B_DIM / 64, A_DIM / 64), 256, 0, stream>>>(
      input, Xt, A_DIM, B_DIM);
  mlgemm_fused<<<dim3((B_DIM / 256) * (D_DIM / 128) * C), 256, 0, stream>>>(
      Xt, wtab, btab, regions, out);
}